// Round 1
// 197.013 us; speedup vs baseline: 1.0416x; 1.0416x over previous
//
#include <hip/hip_runtime.h>
#include <hip/hip_bf16.h>

#define N_NODES 512
#define N_EDGES (512 * 512)
#define NBLK 256                 // sort blocks
#define EPB (N_EDGES / NBLK)     // 1024 edges per sort block

typedef __attribute__((ext_vector_type(2))) _Float16 half2v;

// Hardware dot2: builtin when available, else guaranteed single-instruction asm.
// (The old fdot2_sw fallback cost ~6 VALU ops per dot2 after CSE — if the
// builtin was unavailable at device compile, that alone explains ~2x VALU issue.)
#if defined(__has_builtin)
#if __has_builtin(__builtin_amdgcn_fdot2)
#define FDOT2(a, b, c) __builtin_amdgcn_fdot2((a), (b), (c), false)
#endif
#endif
#ifndef FDOT2
static __device__ inline float fdot2_asm(half2v a, half2v b, float c) {
    float d;
    asm("v_dot2_f32_f16 %0, %1, %2, %3" : "=v"(d) : "v"(a), "v"(b), "v"(c));
    return d;
}
#define FDOT2(a, b, c) fdot2_asm((a), (b), (c))
#endif

static __device__ inline unsigned pack_h2(float x, float y) {
    union { _Float16 h[2]; unsigned u; } c;
    c.h[0] = (_Float16)x;
    c.h[1] = (_Float16)y;
    return c.u;
}
static __device__ inline half2v bits_h2(int b) {
    union { int i; half2v h; } c;
    c.i = b;
    return c.h;
}

// ---------------------------------------------------------------------------
// Deterministic counting sort by dst — NO device-scope atomics.
// count: per-block LDS histogram -> bcnt[block][512]
// ---------------------------------------------------------------------------
__global__ __launch_bounds__(256) void count_kernel(const int* __restrict__ dst,
                                                    int* __restrict__ bcnt) {
    __shared__ int h[N_NODES];
    int tid = threadIdx.x;
    int b = blockIdx.x;
    h[tid] = 0;
    h[tid + 256] = 0;
    __syncthreads();
#pragma unroll
    for (int k = 0; k < EPB / 256; k++)
        atomicAdd(&h[dst[b * EPB + k * 256 + tid]], 1);
    __syncthreads();
    bcnt[b * N_NODES + tid] = h[tid];
    bcnt[b * N_NODES + tid + 256] = h[tid + 256];
}

// ---------------------------------------------------------------------------
// colscan: one block per bucket t. Exclusive prefix of bcnt[b][t] over sort
// blocks b -> pre[b][t]; bucket total -> tot[t]. Replaces the old single-CU
// scan_kernel's two serial 256-iteration passes with 512 parallel blocks.
// ---------------------------------------------------------------------------
__global__ __launch_bounds__(NBLK) void colscan_kernel(const int* __restrict__ bcnt,
                                                       int* __restrict__ pre,
                                                       int* __restrict__ tot) {
    __shared__ int buf[NBLK];
    int t = blockIdx.x;    // bucket (node)
    int b = threadIdx.x;   // sort block
    int v = bcnt[b * N_NODES + t];
    buf[b] = v;
    __syncthreads();
    for (int d = 1; d < NBLK; d <<= 1) {
        int add = (b >= d) ? buf[b - d] : 0;
        __syncthreads();
        buf[b] += add;
        __syncthreads();
    }
    pre[b * N_NODES + t] = buf[b] - v;          // exclusive within bucket
    if (b == NBLK - 1) tot[t] = buf[b];         // bucket total
}

// offs: scan of 512 bucket totals -> offs[513]. Tiny.
__global__ __launch_bounds__(512) void offs_kernel(const int* __restrict__ tot,
                                                   int* __restrict__ offs) {
    __shared__ int buf[N_NODES];
    int t = threadIdx.x;
    int v = tot[t];
    buf[t] = v;
    __syncthreads();
    for (int d = 1; d < N_NODES; d <<= 1) {
        int add = (t >= d) ? buf[t - d] : 0;
        __syncthreads();
        buf[t] += add;
        __syncthreads();
    }
    offs[t + 1] = buf[t];
    if (t == 0) offs[0] = 0;
}

// scatter: LDS cursor seeded from offs[t] + pre[b][t]; LDS atomics only.
__global__ __launch_bounds__(256) void scatter_kernel(const int* __restrict__ src,
                                                      const int* __restrict__ dst,
                                                      const float* __restrict__ ea,
                                                      const int* __restrict__ pre,
                                                      const int* __restrict__ offs,
                                                      int4* __restrict__ ed4) {
    __shared__ int lcur[N_NODES];
    int tid = threadIdx.x;
    int b = blockIdx.x;
    lcur[tid] = offs[tid] + pre[b * N_NODES + tid];
    lcur[tid + 256] = offs[tid + 256] + pre[b * N_NODES + tid + 256];
    __syncthreads();
#pragma unroll
    for (int k = 0; k < EPB / 256; k++) {
        int e = b * EPB + k * 256 + tid;
        const float* a = ea + (size_t)e * 6;
        float a0 = a[0], a1 = a[1], a2 = a[2], a3 = a[3], a4 = a[4], a5 = a[5];
        int p = atomicAdd(&lcur[dst[e]], 1);  // LDS atomic, returns slot
        int4 r;
        r.x = (int)pack_h2(a0, a1);
        r.y = (int)pack_h2(a2, a3);
        r.z = (int)pack_h2(a4, a5);
        r.w = src[e];
        ed4[p] = r;
    }
}

// ---------------------------------------------------------------------------
// NNConv edge pipeline. Lane l (< CIN * COUT/OG) owns input-feature i = l/OPL
// and OG consecutive outputs. Per edge: ONE int4 record (uniform broadcast),
// ONE x[src][i] gather, per o: 3 x v_dot2_f32_f16 + max + fp32 FMA.
// Edge-record loads are software-pipelined one 4-edge batch ahead
// (double-buffered A/B register sets) to break the load->gather->compute
// serial chain that capped VALUBusy at ~63%.
// ---------------------------------------------------------------------------
template <int CIN, int COUT, int OG, int BLK, int G>
__global__ __launch_bounds__(BLK) void nnconv_edges(
    const float* __restrict__ hprev,  // [512, CIN]
    const int4* __restrict__ ed4,     // [E] sorted-by-dst edge records
    const int* __restrict__ offs,     // [513]
    const float* __restrict__ We,     // [6, CIN*COUT] fp32
    const float* __restrict__ be,     // [CIN*COUT]
    float* __restrict__ agg)          // [512, COUT] pre-zeroed
{
    constexpr int J = CIN * COUT;
    constexpr int OPL = COUT / OG;  // o-groups per input feature
    constexpr int A = CIN * OPL;    // active lanes

    const int n = blockIdx.x / G;
    const int g = blockIdx.x % G;
    const int tid = threadIdx.x;
    const bool act = (tid < A);
    const int i = act ? tid / OPL : 0;
    const int og = act ? (tid % OPL) * OG : 0;

    half2v wrp[OG][3];
    float ber[OG], acc[OG];
#pragma unroll
    for (int k = 0; k < OG; k++) {
        acc[k] = 0.f;
        int j = i * COUT + og + k;
        if (act) {
            ber[k] = be[j];
#pragma unroll
            for (int t = 0; t < 3; t++)
                wrp[k][t] = bits_h2((int)pack_h2(We[(2 * t) * J + j], We[(2 * t + 1) * J + j]));
        } else {
            ber[k] = 0.f;
#pragma unroll
            for (int t = 0; t < 3; t++) wrp[k][t] = bits_h2(0);
        }
    }

    const int start = offs[n];
    const int end = offs[n + 1];
    const int len = end - start;
    const int per = (len + G - 1) / G;
    int p = start + g * per;
    int p1 = p + per;
    if (p1 > end) p1 = end;

    // w & 511 bounds the index -> compiler can use v_mad_u32_u24 addressing
    // off the uniform hprev SGPR base (saves 64-bit add per gather).
    auto proc4 = [&](const int4* ed) {
        float xv[4];
#pragma unroll
        for (int u = 0; u < 4; u++)
            xv[u] = hprev[(ed[u].w & (N_NODES - 1)) * CIN + i];
#pragma unroll
        for (int u = 0; u < 4; u++) {
            half2v e01 = bits_h2(ed[u].x), e23 = bits_h2(ed[u].y), e45 = bits_h2(ed[u].z);
#pragma unroll
            for (int k = 0; k < OG; k++) {
                float z = FDOT2(e45, wrp[k][2],
                        FDOT2(e23, wrp[k][1],
                        FDOT2(e01, wrp[k][0], ber[k])));
                acc[k] = fmaf(xv[u], fmaxf(z, 0.f), acc[k]);
            }
        }
    };

    const int nb = (p1 - p) >> 2;  // full 4-edge batches
    {
        const int4* ep = ed4 + p;
        int4 bufA[4], bufB[4];
        if (nb > 0) {
#pragma unroll
            for (int u = 0; u < 4; u++) bufA[u] = ep[u];
            int b = 0;
            while (b + 2 <= nb) {
#pragma unroll
                for (int u = 0; u < 4; u++) bufB[u] = ep[4 + u];  // prefetch b+1
                proc4(bufA);                                       // compute b
                ep += 4; ++b;
                if (b + 2 <= nb) {
#pragma unroll
                    for (int u = 0; u < 4; u++) bufA[u] = ep[4 + u];  // prefetch b+1
                    proc4(bufB);
                    ep += 4; ++b;
                } else {
                    proc4(bufB);
                    ep += 4; ++b;
                }
            }
            if (b < nb) proc4(bufA);
        }
    }
    for (int q = p + (nb << 2); q < p1; ++q) {  // tail (<4 edges)
        int4 ed = ed4[q];
        float xv = hprev[(ed.w & (N_NODES - 1)) * CIN + i];
        half2v e01 = bits_h2(ed.x), e23 = bits_h2(ed.y), e45 = bits_h2(ed.z);
#pragma unroll
        for (int k = 0; k < OG; k++) {
            float z = FDOT2(e45, wrp[k][2],
                    FDOT2(e23, wrp[k][1],
                    FDOT2(e01, wrp[k][0], ber[k])));
            acc[k] = fmaf(xv, fmaxf(z, 0.f), acc[k]);
        }
    }

    if constexpr (CIN == 1) {
        if (act) atomicAdd(&agg[n * COUT + og], acc[0]);
    } else {
        __shared__ float lds_acc[J];
        if (act) {
#pragma unroll
            for (int k = 0; k < OG; k++) lds_acc[i * COUT + og + k] = acc[k];
        }
        __syncthreads();
        if (tid < COUT) {
            float sum = 0.f;
#pragma unroll
            for (int ii = 0; ii < CIN; ii++) sum += lds_acc[ii * COUT + tid];
            atomicAdd(&agg[n * COUT + tid], sum);
        }
    }
}

// ---------------------------------------------------------------------------
// Finalize: mean + root-weight + bias + relu
// ---------------------------------------------------------------------------
template <int CIN, int COUT>
__global__ __launch_bounds__(64) void nnconv_fin(const float* __restrict__ agg,
                                                 const int* __restrict__ offs,
                                                 const float* __restrict__ hprev,
                                                 const float* __restrict__ root,
                                                 const float* __restrict__ bias,
                                                 float* __restrict__ hout) {
    int n = blockIdx.x;
    int t = threadIdx.x;
    if (t >= COUT) return;
    int cnt = offs[n + 1] - offs[n];
    float inv = 1.f / fmaxf((float)cnt, 1.f);
    float v = agg[n * COUT + t] * inv;
#pragma unroll
    for (int i = 0; i < CIN; i++) v = fmaf(hprev[n * CIN + i], root[i * COUT + t], v);
    v += bias[t];
    hout[n * COUT + t] = fmaxf(v, 0.f);
}

// ---------------------------------------------------------------------------
// CBT: out[i,j] = sum_k |h3[i,k] - h3[j,k]|, h3 is [512,5]
// ---------------------------------------------------------------------------
__global__ __launch_bounds__(256) void cbt_kernel(const float* __restrict__ h3,
                                                  float* __restrict__ out) {
    __shared__ float lh[N_NODES * 5];
    int tid = threadIdx.x;
    for (int idx = tid; idx < N_NODES * 5; idx += 256) lh[idx] = h3[idx];
    __syncthreads();
    int i = blockIdx.x;
    float hi[5];
#pragma unroll
    for (int k = 0; k < 5; k++) hi[k] = lh[i * 5 + k];
    for (int j = tid; j < N_NODES; j += 256) {
        float sacc = 0.f;
#pragma unroll
        for (int k = 0; k < 5; k++) sacc += fabsf(hi[k] - lh[j * 5 + k]);
        out[i * N_NODES + j] = sacc;
    }
}

// ---------------------------------------------------------------------------
extern "C" void kernel_launch(void* const* d_in, const int* in_sizes, int n_in,
                              void* d_out, int out_size, void* d_ws, size_t ws_size,
                              hipStream_t stream) {
    const float* x = (const float*)d_in[0];
    const float* edge_attr = (const float*)d_in[1];
    const int* edge_index = (const int*)d_in[2];
    const float* We1 = (const float*)d_in[3];
    const float* be1 = (const float*)d_in[4];
    const float* root1 = (const float*)d_in[5];
    const float* b1 = (const float*)d_in[6];
    const float* We2 = (const float*)d_in[7];
    const float* be2 = (const float*)d_in[8];
    const float* root2 = (const float*)d_in[9];
    const float* b2 = (const float*)d_in[10];
    const float* We3 = (const float*)d_in[11];
    const float* be3 = (const float*)d_in[12];
    const float* root3 = (const float*)d_in[13];
    const float* b3 = (const float*)d_in[14];

    const int E = N_EDGES;
    const int* src = edge_index;
    const int* dst = edge_index + E;

    char* ws = (char*)d_ws;
    int* offs = (int*)(ws + 0);               // 513 ints -> pad to 4096
    int* bcnt = (int*)(ws + 4096);            // 256*512 ints -> ends 528384
    int* pre = (int*)(ws + 528384);           // 256*512 ints -> ends 1052672
    int4* ed4 = (int4*)(ws + 1052672);        // E*16B -> ends 5246976
    // tot aliases the head of ed4: consumed by offs_kernel BEFORE scatter
    // overwrites ed4 (stream-ordered), so no extra workspace needed.
    int* tot = (int*)(ws + 1052672);          // 512 ints, transient
    float* agg1 = (float*)(ws + 5246976);     // 512*36 -> 5320704
    float* agg2 = (float*)(ws + 5320704);     // 512*24 -> 5369856
    float* agg3 = (float*)(ws + 5369856);     // 512*5  -> 5380096
    float* h1 = (float*)(ws + 5380096);       // 512*36 -> 5453824
    float* h2 = (float*)(ws + 5453824);       // 512*24 -> 5502976
    float* h3 = (float*)(ws + 5502976);       // 512*5  -> 5513216

    hipMemsetAsync(agg1, 0, 5380096 - 5246976, stream);  // agg1+agg2+agg3

    count_kernel<<<NBLK, 256, 0, stream>>>(dst, bcnt);
    colscan_kernel<<<N_NODES, NBLK, 0, stream>>>(bcnt, pre, tot);
    offs_kernel<<<1, 512, 0, stream>>>(tot, offs);
    scatter_kernel<<<NBLK, 256, 0, stream>>>(src, dst, edge_attr, pre, offs, ed4);

    // L1: CIN=1, COUT=36, OG=1 -> 36 active lanes, BLK=64, G=16
    nnconv_edges<1, 36, 1, 64, 16><<<N_NODES * 16, 64, 0, stream>>>(x, ed4, offs, We1, be1, agg1);
    nnconv_fin<1, 36><<<N_NODES, 64, 0, stream>>>(agg1, offs, x, root1, b1, h1);

    // L2: CIN=36, COUT=24, OG=4 -> 216 active lanes, BLK=256, G=8
    nnconv_edges<36, 24, 4, 256, 8><<<N_NODES * 8, 256, 0, stream>>>(h1, ed4, offs, We2, be2, agg2);
    nnconv_fin<36, 24><<<N_NODES, 64, 0, stream>>>(agg2, offs, h1, root2, b2, h2);

    // L3: CIN=24, COUT=5, OG=1 -> 120 active lanes, BLK=128, G=8
    nnconv_edges<24, 5, 1, 128, 8><<<N_NODES * 8, 128, 0, stream>>>(h2, ed4, offs, We3, be3, agg3);
    nnconv_fin<24, 5><<<N_NODES, 64, 0, stream>>>(agg3, offs, h2, root3, b3, h3);

    cbt_kernel<<<N_NODES, 256, 0, stream>>>(h3, (float*)d_out);
}

// Round 2
// 190.210 us; speedup vs baseline: 1.0788x; 1.0358x over previous
//
#include <hip/hip_runtime.h>
#include <hip/hip_bf16.h>

#define N_NODES 512
#define N_EDGES (512 * 512)
#define NBLK 256                 // sort blocks
#define EPB (N_EDGES / NBLK)     // 1024 edges per sort block

typedef __attribute__((ext_vector_type(2))) _Float16 half2v;

#if defined(__has_builtin)
#if __has_builtin(__builtin_amdgcn_fdot2)
#define FDOT2(a, b, c) __builtin_amdgcn_fdot2((a), (b), (c), false)
#endif
#if __has_builtin(__builtin_amdgcn_sched_barrier)
#define SB() __builtin_amdgcn_sched_barrier(0)
#endif
#endif
#ifndef FDOT2
static __device__ inline float fdot2_asm(half2v a, half2v b, float c) {
    float d;
    asm("v_dot2_f32_f16 %0, %1, %2, %3" : "=v"(d) : "v"(a), "v"(b), "v"(c));
    return d;
}
#define FDOT2(a, b, c) fdot2_asm((a), (b), (c))
#endif
#ifndef SB
#define SB()
#endif

static __device__ inline unsigned pack_h2(float x, float y) {
    union { _Float16 h[2]; unsigned u; } c;
    c.h[0] = (_Float16)x;
    c.h[1] = (_Float16)y;
    return c.u;
}
static __device__ inline half2v bits_h2(int b) {
    union { int i; half2v h; } c;
    c.i = b;
    return c.h;
}

// ---------------------------------------------------------------------------
// Deterministic counting sort by dst — NO device-scope atomics.
// ---------------------------------------------------------------------------
__global__ __launch_bounds__(256) void count_kernel(const int* __restrict__ dst,
                                                    int* __restrict__ bcnt) {
    __shared__ int h[N_NODES];
    int tid = threadIdx.x;
    int b = blockIdx.x;
    h[tid] = 0;
    h[tid + 256] = 0;
    __syncthreads();
#pragma unroll
    for (int k = 0; k < EPB / 256; k++)
        atomicAdd(&h[dst[b * EPB + k * 256 + tid]], 1);
    __syncthreads();
    bcnt[b * N_NODES + tid] = h[tid];
    bcnt[b * N_NODES + tid + 256] = h[tid + 256];
}

// colscan: one block per bucket t. Exclusive prefix over sort blocks -> pre;
// bucket total -> tot.
__global__ __launch_bounds__(NBLK) void colscan_kernel(const int* __restrict__ bcnt,
                                                       int* __restrict__ pre,
                                                       int* __restrict__ tot) {
    __shared__ int buf[NBLK];
    int t = blockIdx.x;
    int b = threadIdx.x;
    int v = bcnt[b * N_NODES + t];
    buf[b] = v;
    __syncthreads();
    for (int d = 1; d < NBLK; d <<= 1) {
        int add = (b >= d) ? buf[b - d] : 0;
        __syncthreads();
        buf[b] += add;
        __syncthreads();
    }
    pre[b * N_NODES + t] = buf[b] - v;
    if (b == NBLK - 1) tot[t] = buf[b];
}

// offs: scan of 512 bucket totals -> offs[513]. Tiny.
__global__ __launch_bounds__(512) void offs_kernel(const int* __restrict__ tot,
                                                   int* __restrict__ offs) {
    __shared__ int buf[N_NODES];
    int t = threadIdx.x;
    int v = tot[t];
    buf[t] = v;
    __syncthreads();
    for (int d = 1; d < N_NODES; d <<= 1) {
        int add = (t >= d) ? buf[t - d] : 0;
        __syncthreads();
        buf[t] += add;
        __syncthreads();
    }
    offs[t + 1] = buf[t];
    if (t == 0) offs[0] = 0;
}

// scatter: LDS cursor seeded from offs[t] + pre[b][t]; LDS atomics only.
__global__ __launch_bounds__(256) void scatter_kernel(const int* __restrict__ src,
                                                      const int* __restrict__ dst,
                                                      const float* __restrict__ ea,
                                                      const int* __restrict__ pre,
                                                      const int* __restrict__ offs,
                                                      int4* __restrict__ ed4) {
    __shared__ int lcur[N_NODES];
    int tid = threadIdx.x;
    int b = blockIdx.x;
    lcur[tid] = offs[tid] + pre[b * N_NODES + tid];
    lcur[tid + 256] = offs[tid + 256] + pre[b * N_NODES + tid + 256];
    __syncthreads();
#pragma unroll
    for (int k = 0; k < EPB / 256; k++) {
        int e = b * EPB + k * 256 + tid;
        const float* a = ea + (size_t)e * 6;
        float a0 = a[0], a1 = a[1], a2 = a[2], a3 = a[3], a4 = a[4], a5 = a[5];
        int p = atomicAdd(&lcur[dst[e]], 1);
        int4 r;
        r.x = (int)pack_h2(a0, a1);
        r.y = (int)pack_h2(a2, a3);
        r.z = (int)pack_h2(a4, a5);
        r.w = src[e];
        ed4[p] = r;
    }
}

// ---------------------------------------------------------------------------
// NNConv edge pipeline with explicit 3-stage rotating software pipeline:
//   line k: issue ed-load for batch k+2 | issue x-gathers for batch k+1
//           | sched_barrier | compute batch k
// Loads run 2 batches ahead, gathers 1 ahead -> both memory latencies hide
// under compute. sched_barrier(0) pins the issue order so the compiler cannot
// re-serialize the pipeline (round-1 failure mode: VGPR collapsed to 24).
// ---------------------------------------------------------------------------
template <int CIN, int COUT, int OG, int BLK, int G>
__global__ __launch_bounds__(BLK) void nnconv_edges(
    const float* __restrict__ hprev,  // [512, CIN]
    const int4* __restrict__ ed4,     // [E] sorted-by-dst edge records
    const int* __restrict__ offs,     // [513]
    const float* __restrict__ We,     // [6, CIN*COUT] fp32
    const float* __restrict__ be,     // [CIN*COUT]
    float* __restrict__ agg)          // [512, COUT] pre-zeroed
{
    constexpr int J = CIN * COUT;
    constexpr int OPL = COUT / OG;  // o-groups per input feature
    constexpr int A = CIN * OPL;    // active lanes

    const int n = blockIdx.x / G;
    const int g = blockIdx.x % G;
    const int tid = threadIdx.x;
    const bool act = (tid < A);
    const int i = act ? tid / OPL : 0;
    const int og = act ? (tid % OPL) * OG : 0;

    half2v wrp[OG][3];
    float ber[OG], acc[OG];
#pragma unroll
    for (int k = 0; k < OG; k++) {
        acc[k] = 0.f;
        int j = i * COUT + og + k;
        if (act) {
            ber[k] = be[j];
#pragma unroll
            for (int t = 0; t < 3; t++)
                wrp[k][t] = bits_h2((int)pack_h2(We[(2 * t) * J + j], We[(2 * t + 1) * J + j]));
        } else {
            ber[k] = 0.f;
#pragma unroll
            for (int t = 0; t < 3; t++) wrp[k][t] = bits_h2(0);
        }
    }

    const int start = offs[n];
    const int end = offs[n + 1];
    const int len = end - start;
    const int per = (len + G - 1) / G;
    int p = start + g * per;
    int p1 = p + per;
    if (p1 > end) p1 = end;

    const float* hp_i = hprev + i;  // per-lane feature-column base

    // static-index helpers (all calls fully unrolled -> register-resident)
    auto ld4 = [&](int4* d, const int4* ep) {
#pragma unroll
        for (int u = 0; u < 4; u++) d[u] = ep[u];
    };
    auto g4 = [&](float* xv, const int4* ed) {
#pragma unroll
        for (int u = 0; u < 4; u++) xv[u] = hp_i[(ed[u].w & (N_NODES - 1)) * CIN];
    };
    auto c4 = [&](const int4* ed, const float* xv) {
#pragma unroll
        for (int u = 0; u < 4; u++) {
            half2v e01 = bits_h2(ed[u].x), e23 = bits_h2(ed[u].y), e45 = bits_h2(ed[u].z);
#pragma unroll
            for (int k = 0; k < OG; k++) {
                float z = FDOT2(e45, wrp[k][2],
                        FDOT2(e23, wrp[k][1],
                        FDOT2(e01, wrp[k][0], ber[k])));
                acc[k] = fmaf(xv[u], fmaxf(z, 0.f), acc[k]);
            }
        }
    };

    const int nb = (p1 - p) >> 2;  // full 4-edge batches
    const int4* ep = ed4 + p;
    int k = 0;
    if (nb >= 3) {
        int4 eA[4], eB[4], eC[4];
        float xA[4], xB[4], xC[4];
        ld4(eA, ep);
        ld4(eB, ep + 4);
        g4(xA, eA);
        // invariant at loop top: eA=batch k (xA ready), eB=batch k+1 loaded.
        // in-loop prefetch may read <=1.3KB past the slice end — stays inside
        // the ed4 workspace region; gather index is masked, so harmless.
        while (k + 3 <= nb) {
            ld4(eC, ep + 8);
            g4(xB, eB);
            SB();
            c4(eA, xA);
            ld4(eA, ep + 12);
            g4(xC, eC);
            SB();
            c4(eB, xB);
            ld4(eB, ep + 16);
            g4(xA, eA);
            SB();
            c4(eC, xC);
            ep += 12;
            k += 3;
        }
        int m = nb - k;
        if (m >= 1) c4(eA, xA);
        if (m >= 2) {
            g4(xB, eB);
            c4(eB, xB);
        }
        k = nb;
        ep = ed4 + p + (nb << 2);
    }
    // non-pipelined path (nb < 3 leftovers handled above; here nb<3 case)
    for (; k < nb; ++k) {
        int4 e[4];
        float xv[4];
        ld4(e, ep);
        g4(xv, e);
        c4(e, xv);
        ep += 4;
    }
    for (int q = p + (nb << 2); q < p1; ++q) {  // tail (<4 edges)
        int4 ed = ed4[q];
        float xv = hp_i[(ed.w & (N_NODES - 1)) * CIN];
        half2v e01 = bits_h2(ed.x), e23 = bits_h2(ed.y), e45 = bits_h2(ed.z);
#pragma unroll
        for (int kk = 0; kk < OG; kk++) {
            float z = FDOT2(e45, wrp[kk][2],
                    FDOT2(e23, wrp[kk][1],
                    FDOT2(e01, wrp[kk][0], ber[kk])));
            acc[kk] = fmaf(xv, fmaxf(z, 0.f), acc[kk]);
        }
    }

    if constexpr (CIN == 1) {
        if (act) atomicAdd(&agg[n * COUT + og], acc[0]);
    } else {
        __shared__ float lds_acc[J];
        if (act) {
#pragma unroll
            for (int k2 = 0; k2 < OG; k2++) lds_acc[i * COUT + og + k2] = acc[k2];
        }
        __syncthreads();
        if (tid < COUT) {
            float sum = 0.f;
#pragma unroll
            for (int ii = 0; ii < CIN; ii++) sum += lds_acc[ii * COUT + tid];
            atomicAdd(&agg[n * COUT + tid], sum);
        }
    }
}

// ---------------------------------------------------------------------------
// Finalize: mean + root-weight + bias + relu
// ---------------------------------------------------------------------------
template <int CIN, int COUT>
__global__ __launch_bounds__(64) void nnconv_fin(const float* __restrict__ agg,
                                                 const int* __restrict__ offs,
                                                 const float* __restrict__ hprev,
                                                 const float* __restrict__ root,
                                                 const float* __restrict__ bias,
                                                 float* __restrict__ hout) {
    int n = blockIdx.x;
    int t = threadIdx.x;
    if (t >= COUT) return;
    int cnt = offs[n + 1] - offs[n];
    float inv = 1.f / fmaxf((float)cnt, 1.f);
    float v = agg[n * COUT + t] * inv;
#pragma unroll
    for (int i = 0; i < CIN; i++) v = fmaf(hprev[n * CIN + i], root[i * COUT + t], v);
    v += bias[t];
    hout[n * COUT + t] = fmaxf(v, 0.f);
}

// ---------------------------------------------------------------------------
// CBT: out[i,j] = sum_k |h3[i,k] - h3[j,k]|, h3 is [512,5]
// ---------------------------------------------------------------------------
__global__ __launch_bounds__(256) void cbt_kernel(const float* __restrict__ h3,
                                                  float* __restrict__ out) {
    __shared__ float lh[N_NODES * 5];
    int tid = threadIdx.x;
    for (int idx = tid; idx < N_NODES * 5; idx += 256) lh[idx] = h3[idx];
    __syncthreads();
    int i = blockIdx.x;
    float hi[5];
#pragma unroll
    for (int k = 0; k < 5; k++) hi[k] = lh[i * 5 + k];
    for (int j = tid; j < N_NODES; j += 256) {
        float sacc = 0.f;
#pragma unroll
        for (int k = 0; k < 5; k++) sacc += fabsf(hi[k] - lh[j * 5 + k]);
        out[i * N_NODES + j] = sacc;
    }
}

// ---------------------------------------------------------------------------
extern "C" void kernel_launch(void* const* d_in, const int* in_sizes, int n_in,
                              void* d_out, int out_size, void* d_ws, size_t ws_size,
                              hipStream_t stream) {
    const float* x = (const float*)d_in[0];
    const float* edge_attr = (const float*)d_in[1];
    const int* edge_index = (const int*)d_in[2];
    const float* We1 = (const float*)d_in[3];
    const float* be1 = (const float*)d_in[4];
    const float* root1 = (const float*)d_in[5];
    const float* b1 = (const float*)d_in[6];
    const float* We2 = (const float*)d_in[7];
    const float* be2 = (const float*)d_in[8];
    const float* root2 = (const float*)d_in[9];
    const float* b2 = (const float*)d_in[10];
    const float* We3 = (const float*)d_in[11];
    const float* be3 = (const float*)d_in[12];
    const float* root3 = (const float*)d_in[13];
    const float* b3 = (const float*)d_in[14];

    const int E = N_EDGES;
    const int* src = edge_index;
    const int* dst = edge_index + E;

    char* ws = (char*)d_ws;
    int* offs = (int*)(ws + 0);               // 513 ints
    int* tot = (int*)(ws + 2048);             // 512 ints (fits in offs pad)
    int* bcnt = (int*)(ws + 4096);            // 256*512 ints -> ends 528384
    int* pre = (int*)(ws + 528384);           // 256*512 ints -> ends 1052672
    int4* ed4 = (int4*)(ws + 1052672);        // E*16B -> ends 5246976
    float* agg1 = (float*)(ws + 5246976);     // 512*36 -> 5320704
    float* agg2 = (float*)(ws + 5320704);     // 512*24 -> 5369856
    float* agg3 = (float*)(ws + 5369856);     // 512*5  -> 5380096
    float* h1 = (float*)(ws + 5380096);       // 512*36 -> 5453824
    float* h2 = (float*)(ws + 5453824);       // 512*24 -> 5502976
    float* h3 = (float*)(ws + 5502976);       // 512*5  -> 5513216

    hipMemsetAsync(agg1, 0, 5380096 - 5246976, stream);  // agg1+agg2+agg3

    count_kernel<<<NBLK, 256, 0, stream>>>(dst, bcnt);
    colscan_kernel<<<N_NODES, NBLK, 0, stream>>>(bcnt, pre, tot);
    offs_kernel<<<1, 512, 0, stream>>>(tot, offs);
    scatter_kernel<<<NBLK, 256, 0, stream>>>(src, dst, edge_attr, pre, offs, ed4);

    // L1: CIN=1, COUT=36, OG=1 -> 36 active lanes, BLK=64, G=16
    nnconv_edges<1, 36, 1, 64, 16><<<N_NODES * 16, 64, 0, stream>>>(x, ed4, offs, We1, be1, agg1);
    nnconv_fin<1, 36><<<N_NODES, 64, 0, stream>>>(agg1, offs, x, root1, b1, h1);

    // L2: CIN=36, COUT=24, OG=4 -> 216 active lanes, BLK=256, G=8
    nnconv_edges<36, 24, 4, 256, 8><<<N_NODES * 8, 256, 0, stream>>>(h1, ed4, offs, We2, be2, agg2);
    nnconv_fin<36, 24><<<N_NODES, 64, 0, stream>>>(agg2, offs, h1, root2, b2, h2);

    // L3: CIN=24, COUT=5, OG=1 -> 120 active lanes, BLK=128, G=8
    nnconv_edges<24, 5, 1, 128, 8><<<N_NODES * 8, 128, 0, stream>>>(h2, ed4, offs, We3, be3, agg3);
    nnconv_fin<24, 5><<<N_NODES, 64, 0, stream>>>(agg3, offs, h2, root3, b3, h3);

    cbt_kernel<<<N_NODES, 256, 0, stream>>>(h3, (float*)d_out);
}